// Round 15
// baseline (1039.928 us; speedup 1.0000x reference)
//
#include <hip/hip_runtime.h>
#include <hip/hip_bf16.h>
#include <math.h>

#define D_ 1024
#define H_ 16
#define F_ 4096
#define S_ 1024
#define B_ 2
#define MTOT 2048   // B_*S_

using bf16 = __hip_bfloat16;
typedef __bf16 bf16x8 __attribute__((ext_vector_type(8)));
typedef float f32x4 __attribute__((ext_vector_type(4)));

__device__ __forceinline__ void gload_lds16(const void* g, void* l) {
  __builtin_amdgcn_global_load_lds((const __attribute__((address_space(1))) void*)g,
                                   (__attribute__((address_space(3))) void*)l, 16, 0, 0);
}

__device__ __forceinline__ unsigned short f2b(float f) {
  union { bf16 h; unsigned short u; } c;
  c.h = __float2bfloat16(f);
  return c.u;
}

__device__ __forceinline__ unsigned pk2(float a, float b) {
  return (unsigned)f2b(a) | ((unsigned)f2b(b) << 16);
}

// ---------------- embedding: x = emb[id]*sqrt(D) + pos ----------------
__global__ __launch_bounds__(256) void embed_kernel(const int* __restrict__ ids,
    const float* __restrict__ emb, const float* __restrict__ pos, float* __restrict__ x) {
  int row = blockIdx.x;              // 0..2047 = b*S + s
  int s = row & (S_ - 1);
  int id = ids[row];
  const float4* e = (const float4*)(emb + (size_t)id * D_);
  const float4* p = (const float4*)(pos + (size_t)s * D_);
  float4* xo = (float4*)(x + (size_t)row * D_);
  int t = threadIdx.x;               // 256 threads * 4 floats = 1024
  float4 ev = e[t], pv = p[t], r;
  r.x = ev.x * 32.0f + pv.x; r.y = ev.y * 32.0f + pv.y;
  r.z = ev.z * 32.0f + pv.z; r.w = ev.w * 32.0f + pv.w;
  xo[t] = r;
}

// ---------------- layernorm (f32 in) -> bf16 out: wave-per-row ----------------
// 4 rows/block (one per wave), shfl_xor reduce only -- no LDS, no barriers.
__global__ __launch_bounds__(256) void ln_kernel(const float* __restrict__ x,
    const float* __restrict__ w, const float* __restrict__ b, bf16* __restrict__ h) {
  int wave = threadIdx.x >> 6, lane = threadIdx.x & 63;
  int row = blockIdx.x * 4 + wave;
  const float4* xr = (const float4*)(x + (size_t)row * D_);
  float4 v[4];
  float s = 0.f, s2 = 0.f;
  #pragma unroll
  for (int k = 0; k < 4; k++) {
    v[k] = xr[lane + 64 * k];
    s  += v[k].x + v[k].y + v[k].z + v[k].w;
    s2 += v[k].x * v[k].x + v[k].y * v[k].y + v[k].z * v[k].z + v[k].w * v[k].w;
  }
  #pragma unroll
  for (int o = 32; o; o >>= 1) { s += __shfl_xor(s, o); s2 += __shfl_xor(s2, o); }
  float mean = s * (1.0f / D_);
  float m2   = s2 * (1.0f / D_);
  float rstd = rsqrtf(m2 - mean * mean + 1e-5f);
  ushort4* ho = (ushort4*)(h + (size_t)row * D_);
  #pragma unroll
  for (int k = 0; k < 4; k++) {
    float4 wv = ((const float4*)w)[lane + 64 * k];
    float4 bv = ((const float4*)b)[lane + 64 * k];
    ushort4 o4;
    o4.x = f2b((v[k].x - mean) * rstd * wv.x + bv.x);
    o4.y = f2b((v[k].y - mean) * rstd * wv.y + bv.y);
    o4.z = f2b((v[k].z - mean) * rstd * wv.z + bv.z);
    o4.w = f2b((v[k].w - mean) * rstd * wv.w + bv.w);
    ho[lane + 64 * k] = o4;
  }
}

// ------------- weight conversion: stream f32 -> bf16, per-layer strided dst ---
template<int LSHIFT>
__global__ __launch_bounds__(256) void cvt_copy_kernel(const float4* __restrict__ src,
    ushort4* __restrict__ dst, int n4, int wl4) {
  int stride = gridDim.x * 256;
  for (int i = blockIdx.x * 256 + threadIdx.x; i < n4; i += stride) {
    int layer = i >> LSHIFT;
    int r = i & ((1 << LSHIFT) - 1);
    float4 v = src[i];
    ushort4 p;
    p.x = f2b(v.x); p.y = f2b(v.y); p.z = f2b(v.z); p.w = f2b(v.w);
    dst[(size_t)layer * wl4 + r] = p;
  }
}

// ---------------- GEMM: C[M,N] = A[M,K] @ B[N,K]^T (+bias, epilogue by MODE) ---
// round-2 measured-best structure (setprio, 2-buffer 2-phase, XOR swizzle).
template<int MODE>
__global__ __launch_bounds__(256) void gemm_bt(const bf16* __restrict__ A,
    const bf16* __restrict__ Bw,
    const float* __restrict__ b0_, const float* __restrict__ b1_, const float* __restrict__ b2_,
    void* __restrict__ o0, void* __restrict__ o1, void* __restrict__ o2,
    int M, int N, int K, int kspl) {
  __shared__ alignas(16) bf16 As[2][128 * 64];
  __shared__ alignas(16) bf16 Bs[2][128 * 64];
  int tid = threadIdx.x, wave = tid >> 6, lane = tid & 63;
  int nbn = N >> 7;
  int nwg = gridDim.x;
  int bid = blockIdx.x;
  int swz = (bid & 7) * (nwg >> 3) + (bid >> 3);
  int bm = swz / nbn, bn = swz % nbn;
  int m0 = bm << 7, n0 = bn << 7;
  int kbase = blockIdx.z * kspl;
  int wr = wave >> 1, wc = wave & 1;
  int lr = lane & 15, lg = lane >> 4;

  auto stage = [&](int buf, int k0) {
    #pragma unroll
    for (int j = 0; j < 4; j++) {
      int cidx = j * 256 + tid;          // chunk 0..1023
      int r = cidx >> 3, s = cidx & 7;
      int g = s ^ (r & 7);
      bf16* abase = &As[buf][(j * 256 + wave * 64) * 8];
      bf16* bbase = &Bs[buf][(j * 256 + wave * 64) * 8];
      gload_lds16(A  + (size_t)(m0 + r) * K + k0 + g * 8, abase);
      gload_lds16(Bw + (size_t)(n0 + r) * K + k0 + g * 8, bbase);
    }
  };

  f32x4 acc[4][4] = {};
  int nk = kspl >> 6;
  stage(0, kbase);
  __syncthreads();
  int cur = 0;
  for (int t = 0; t < nk; ++t) {
    if (t + 1 < nk) stage(cur ^ 1, kbase + (t + 1) * 64);
    __builtin_amdgcn_s_setprio(1);
    #pragma unroll
    for (int kk = 0; kk < 2; ++kk) {
      bf16x8 af[4], bfr[4];
      #pragma unroll
      for (int f = 0; f < 4; f++) {
        int ra = wr * 64 + f * 16 + lr;
        int rb = wc * 64 + f * 16 + lr;
        af[f]  = *(const bf16x8*)&As[cur][ra * 64 + (((kk * 4 + lg) ^ (ra & 7)) * 8)];
        bfr[f] = *(const bf16x8*)&Bs[cur][rb * 64 + (((kk * 4 + lg) ^ (rb & 7)) * 8)];
      }
      #pragma unroll
      for (int mf = 0; mf < 4; mf++)
        #pragma unroll
        for (int nf = 0; nf < 4; nf++)
          acc[mf][nf] = __builtin_amdgcn_mfma_f32_16x16x32_bf16(af[mf], bfr[nf], acc[mf][nf], 0, 0, 0);
    }
    __builtin_amdgcn_s_setprio(0);
    __syncthreads();
    cur ^= 1;
  }

  #pragma unroll
  for (int mf = 0; mf < 4; mf++) {
    #pragma unroll
    for (int nf = 0; nf < 4; nf++) {
      int n = n0 + wc * 64 + nf * 16 + lr;
      if (MODE == 0 && n >= 2048) {
        int nl = n & 1023;
        int mbase = m0 + wr * 64 + mf * 16 + lg * 4;
        int bb = mbase >> 10, sb = mbase & 1023;
        float bias = b2_[nl];
        ushort4 pk;
        pk.x = f2b(acc[mf][nf][0] + bias);
        pk.y = f2b(acc[mf][nf][1] + bias);
        pk.z = f2b(acc[mf][nf][2] + bias);
        pk.w = f2b(acc[mf][nf][3] + bias);
        *(ushort4*)&((bf16*)o2)[((size_t)(bb * 1024 + nl)) * 1024 + sb] = pk;
      } else {
        #pragma unroll
        for (int i = 0; i < 4; i++) {
          int m = m0 + wr * 64 + mf * 16 + lg * 4 + i;
          float v = acc[mf][nf][i];
          if (MODE == 0) {
            int seg = n >> 10, nl = n & 1023;
            if (seg == 0)      ((bf16*)o0)[(size_t)m * 1024 + nl] = __float2bfloat16(v + b0_[nl]);
            else               ((bf16*)o1)[(size_t)m * 1024 + nl] = __float2bfloat16(v + b1_[nl]);
          } else if (MODE == 1) {
            float bias = (blockIdx.z == 0) ? b0_[n] : 0.0f;
            atomicAdd(&((float*)o0)[(size_t)m * N + n], v + bias);
          } else {
            float g = v + b0_[n];
            float e = __expf(-1.5957691216057308f * (g + 0.044715f * g * g * g));
            ((bf16*)o0)[(size_t)m * N + n] = __float2bfloat16(g / (1.0f + e));
          }
        }
      }
    }
  }
}

// ---------------- flash attention: block = 64 q-rows (4 waves x 16) -----------
// KVBLK=128, swapped QK^T, in-register online softmax in EXP2 DOMAIN
// (t = s * 0.125*log2e; p = 2^(t - mu) == e^(s - m); THR 8 -> 11.54).
// K tile [128k][64d] (8-slot XOR) / V^T tile [64d][128k] (16-slot XOR),
// double-buffered 2-phase. Grid (32 bh, 16 qblk): KV-sharing blocks land on
// the same XCD (linear id == bh mod 8).
__global__ __launch_bounds__(256) void attn_kernel(const bf16* __restrict__ qbuf,
    const bf16* __restrict__ kbuf, const bf16* __restrict__ vT, bf16* __restrict__ obuf) {
  int bh = blockIdx.x;                 // 0..31  (XCD-locality)
  int b = bh >> 4, h = bh & 15;
  int qblk = blockIdx.y * 64;
  int tid = threadIdx.x, wave = tid >> 6, lane = tid & 63;
  int lr = lane & 15, lg = lane >> 4;

  __shared__ alignas(16) bf16 Ks[2][128 * 64];  // [key][d], 8x16B XOR slots
  __shared__ alignas(16) bf16 Vs[2][64 * 128];  // [d][key], 16x16B XOR slots

  auto stage = [&](int buf, int c) {
    int kb = c * 128;
    #pragma unroll
    for (int j = 0; j < 4; j++) {      // K: 1024 chunks, 8 per key-row
      int cidx = j * 256 + tid;
      int r = cidx >> 3, s = cidx & 7, g = s ^ (r & 7);
      gload_lds16(kbuf + (size_t)(b * S_ + kb + r) * D_ + h * 64 + g * 8,
                  &Ks[buf][(j * 256 + wave * 64) * 8]);
    }
    #pragma unroll
    for (int j = 0; j < 4; j++) {      // V: 1024 chunks, 16 per d-row
      int cidx = j * 256 + tid;
      int r = cidx >> 4, s = cidx & 15, g = s ^ (r & 15);
      gload_lds16(vT + (size_t)(b * D_ + h * 64 + r) * S_ + kb + g * 8,
                  &Vs[buf][(j * 256 + wave * 64) * 8]);
    }
  };

  const bf16* qp = qbuf + (size_t)(b * S_ + qblk + wave * 16 + lr) * D_ + h * 64;
  bf16x8 qf0 = *(const bf16x8*)(qp + lg * 8);
  bf16x8 qf1 = *(const bf16x8*)(qp + 32 + lg * 8);

  f32x4 oacc[4] = {};                  // O[q=lg*4+i][d=nf*16+lr]
  float m_run = -1e30f, l_run = 0.0f;  // in exp2 (t) domain
  int x7 = lr & 7;
  const float SC = 0.18033688011112042f;   // 0.125 * log2(e)
  const float THR = 11.541560327111707f;   // 8 * log2(e)

  stage(0, 0);
  __syncthreads();
  int cur = 0;
  for (int c = 0; c < 8; ++c) {
    if (c + 1 < 8) stage(cur ^ 1, c + 1);

    float p[32];
    __builtin_amdgcn_s_setprio(1);
    #pragma unroll
    for (int kg = 0; kg < 8; kg++) {
      int row = kg * 16 + lr;
      bf16x8 k0 = *(const bf16x8*)&Ks[cur][row * 64 + ((lg ^ x7) * 8)];
      bf16x8 k1 = *(const bf16x8*)&Ks[cur][row * 64 + (((4 + lg) ^ x7) * 8)];
      f32x4 s = {};
      s = __builtin_amdgcn_mfma_f32_16x16x32_bf16(k0, qf0, s, 0, 0, 0);
      s = __builtin_amdgcn_mfma_f32_16x16x32_bf16(k1, qf1, s, 0, 0, 0);
      #pragma unroll
      for (int i = 0; i < 4; i++) p[kg * 4 + i] = s[i] * SC;
    }
    __builtin_amdgcn_s_setprio(0);

    float cmax = p[0];
    #pragma unroll
    for (int j = 1; j < 32; j++) cmax = fmaxf(cmax, p[j]);
    cmax = fmaxf(cmax, __shfl_xor(cmax, 16));
    cmax = fmaxf(cmax, __shfl_xor(cmax, 32));

    if (__any(cmax > m_run + THR)) {
      float m_new = fmaxf(m_run, cmax);
      float fsc = exp2f(m_run - m_new);
      m_run = m_new;
      float f0 = __shfl(fsc, lg * 4 + 0);
      float f1 = __shfl(fsc, lg * 4 + 1);
      float f2 = __shfl(fsc, lg * 4 + 2);
      float f3 = __shfl(fsc, lg * 4 + 3);
      #pragma unroll
      for (int nf = 0; nf < 4; nf++) {
        oacc[nf][0] *= f0; oacc[nf][1] *= f1; oacc[nf][2] *= f2; oacc[nf][3] *= f3;
      }
      l_run *= fsc;
    }

    float csum = 0.0f;
    #pragma unroll
    for (int j = 0; j < 32; j++) { p[j] = exp2f(p[j] - m_run); csum += p[j]; }
    csum += __shfl_xor(csum, 16);
    csum += __shfl_xor(csum, 32);
    l_run += csum;

    bf16x8 pf[4];
    int slo = 32 * (lg & 1) + lr, shi = slo + 16;
    bool loh = (lg < 2);
    #pragma unroll
    for (int ks = 0; ks < 4; ks++) {
      unsigned A0 = pk2(p[ks * 8 + 0], p[ks * 8 + 1]);
      unsigned A1 = pk2(p[ks * 8 + 2], p[ks * 8 + 3]);
      unsigned B0 = pk2(p[ks * 8 + 4], p[ks * 8 + 5]);
      unsigned B1 = pk2(p[ks * 8 + 6], p[ks * 8 + 7]);
      unsigned tA0 = __shfl(A0, slo), tB0 = __shfl(B0, slo);
      unsigned tA1 = __shfl(A1, slo), tB1 = __shfl(B1, slo);
      unsigned uA0 = __shfl(A0, shi), uB0 = __shfl(B0, shi);
      unsigned uA1 = __shfl(A1, shi), uB1 = __shfl(B1, shi);
      union { unsigned w[4]; bf16x8 v; } pfu;
      pfu.w[0] = loh ? tA0 : tB0;
      pfu.w[1] = loh ? tA1 : tB1;
      pfu.w[2] = loh ? uA0 : uB0;
      pfu.w[3] = loh ? uA1 : uB1;
      pf[ks] = pfu.v;
    }

    __builtin_amdgcn_s_setprio(1);
    #pragma unroll
    for (int nf = 0; nf < 4; nf++) {
      int rv = nf * 16 + lr;
      int xv = rv & 15;
      #pragma unroll
      for (int ks = 0; ks < 4; ks++) {
        bf16x8 vf = *(const bf16x8*)&Vs[cur][rv * 128 + (((ks * 4 + lg) ^ xv) * 8)];
        oacc[nf] = __builtin_amdgcn_mfma_f32_16x16x32_bf16(pf[ks], vf, oacc[nf], 0, 0, 0);
      }
    }
    __builtin_amdgcn_s_setprio(0);

    __syncthreads();
    cur ^= 1;
  }

  float l0 = __shfl(l_run, lg * 4 + 0);
  float l1 = __shfl(l_run, lg * 4 + 1);
  float l2 = __shfl(l_run, lg * 4 + 2);
  float l3 = __shfl(l_run, lg * 4 + 3);
  float li[4] = {l0, l1, l2, l3};
  #pragma unroll
  for (int i = 0; i < 4; i++) {
    size_t row = (size_t)(b * S_ + qblk + wave * 16 + lg * 4 + i) * D_ + h * 64;
    #pragma unroll
    for (int nf = 0; nf < 4; nf++)
      obuf[row + nf * 16 + lr] = __float2bfloat16(oacc[nf][i] / li[i]);
  }
}

// ---------------- host launch ----------------
extern "C" void kernel_launch(void* const* d_in, const int* in_sizes, int n_in,
                              void* d_out, int out_size, void* d_ws, size_t ws_size,
                              hipStream_t stream) {
  const int*   ids  = (const int*)d_in[0];
  // d_in[1] = attention_mask (all true) -- unused
  const float* emb  = (const float*)d_in[2];
  const float* pos  = (const float*)d_in[3];
  const float* ln1w = (const float*)d_in[4];
  const float* ln1b = (const float*)d_in[5];
  const float* qw = (const float*)d_in[6];  const float* qb = (const float*)d_in[7];
  const float* kw = (const float*)d_in[8];  const float* kb = (const float*)d_in[9];
  const float* vw = (const float*)d_in[10]; const float* vb = (const float*)d_in[11];
  const float* ow = (const float*)d_in[12]; const float* ob = (const float*)d_in[13];
  const float* ln2w = (const float*)d_in[14]; const float* ln2b = (const float*)d_in[15];
  const float* w1 = (const float*)d_in[16]; const float* b1 = (const float*)d_in[17];
  const float* w2 = (const float*)d_in[18]; const float* b2 = (const float*)d_in[19];
  (void)in_sizes; (void)n_in; (void)out_size; (void)ws_size;

  float* x = (float*)d_out;            // residual stream lives in d_out (f32 [2048][1024])
  char* ws = (char*)d_ws;
  const size_t SZ_ACT = (size_t)MTOT * D_ * 2;       // 4 MB bf16
  bf16* h    = (bf16*)(ws);
  bf16* q    = (bf16*)(ws + SZ_ACT);
  bf16* k    = (bf16*)(ws + 2 * SZ_ACT);
  bf16* vt   = (bf16*)(ws + 3 * SZ_ACT);
  bf16* o    = (bf16*)(ws + 4 * SZ_ACT);
  bf16* mid  = (bf16*)(ws + 5 * SZ_ACT);             // 16 MB
  bf16* wbuf = (bf16*)(ws + 5 * SZ_ACT + (size_t)MTOT * F_ * 2);  // 151 MB (layer-major)

  const size_t DD = (size_t)D_ * D_;       // 1048576 (2^20)
  const size_t FD = (size_t)F_ * D_;       // 4194304 (2^22)
  const size_t WL = 4 * DD + 2 * FD;       // 12582912 elements per layer

  const int WL4 = (int)(WL / 4);
  cvt_copy_kernel<18><<<2048, 256, 0, stream>>>((const float4*)qw,
      (ushort4*)(wbuf + 0 * DD), (int)(6 * DD / 4), WL4);
  cvt_copy_kernel<18><<<2048, 256, 0, stream>>>((const float4*)kw,
      (ushort4*)(wbuf + 1 * DD), (int)(6 * DD / 4), WL4);
  cvt_copy_kernel<18><<<2048, 256, 0, stream>>>((const float4*)vw,
      (ushort4*)(wbuf + 2 * DD), (int)(6 * DD / 4), WL4);
  cvt_copy_kernel<18><<<2048, 256, 0, stream>>>((const float4*)ow,
      (ushort4*)(wbuf + 3 * DD), (int)(6 * DD / 4), WL4);
  cvt_copy_kernel<20><<<2048, 256, 0, stream>>>((const float4*)w1,
      (ushort4*)(wbuf + 4 * DD), (int)(6 * FD / 4), WL4);
  cvt_copy_kernel<20><<<2048, 256, 0, stream>>>((const float4*)w2,
      (ushort4*)(wbuf + 4 * DD + FD), (int)(6 * FD / 4), WL4);

  embed_kernel<<<MTOT, 256, 0, stream>>>(ids, emb, pos, x);

  for (int l = 0; l < 6; l++) {
    bf16* wl = wbuf + (size_t)l * WL;

    ln_kernel<<<MTOT / 4, 256, 0, stream>>>(x, ln1w + l * D_, ln1b + l * D_, h);

    // fused QKV: N = 3072, 384 blocks ([qw|kw|vw] contiguous in wl)
    gemm_bt<0><<<dim3(384, 1, 1), 256, 0, stream>>>(h, wl,
        qb + l * D_, kb + l * D_, vb + l * D_, q, k, vt, MTOT, 3072, 1024, 1024);

    // flash attention: 32 (b,h) x 16 q-blocks (XCD-locality axis order)
    attn_kernel<<<dim3(32, 16), 256, 0, stream>>>(q, k, vt, o);

    // x += o @ ow^T + ob   (split-K=2 -> 256 blocks)
    gemm_bt<1><<<dim3(128, 1, 2), 256, 0, stream>>>(o, wl + 3 * DD,
        ob + l * D_, nullptr, nullptr, x, nullptr, nullptr, MTOT, 1024, 1024, 512);

    ln_kernel<<<MTOT / 4, 256, 0, stream>>>(x, ln2w + l * D_, ln2b + l * D_, h);

    // mid = gelu(h @ w1^T + b1), 512 blocks
    gemm_bt<2><<<dim3(512, 1, 1), 256, 0, stream>>>(h, wl + 4 * DD,
        b1 + l * F_, nullptr, nullptr, mid, nullptr, nullptr, MTOT, 4096, 1024, 1024);

    // x += mid @ w2^T + b2   (split-K=2 -> 256 blocks)
    gemm_bt<1><<<dim3(128, 1, 2), 256, 0, stream>>>(mid, wl + 4 * DD + FD,
        b2 + l * D_, nullptr, nullptr, x, nullptr, nullptr, MTOT, 1024, 4096, 2048);
  }
}

// Round 16
// 1036.092 us; speedup vs baseline: 1.0037x; 1.0037x over previous
//
#include <hip/hip_runtime.h>
#include <hip/hip_bf16.h>
#include <math.h>

#define D_ 1024
#define H_ 16
#define F_ 4096
#define S_ 1024
#define B_ 2
#define MTOT 2048   // B_*S_

using bf16 = __hip_bfloat16;
typedef __bf16 bf16x8 __attribute__((ext_vector_type(8)));
typedef float f32x4 __attribute__((ext_vector_type(4)));

__device__ __forceinline__ void gload_lds16(const void* g, void* l) {
  __builtin_amdgcn_global_load_lds((const __attribute__((address_space(1))) void*)g,
                                   (__attribute__((address_space(3))) void*)l, 16, 0, 0);
}

__device__ __forceinline__ unsigned short f2b(float f) {
  union { bf16 h; unsigned short u; } c;
  c.h = __float2bfloat16(f);
  return c.u;
}

__device__ __forceinline__ unsigned pk2(float a, float b) {
  return (unsigned)f2b(a) | ((unsigned)f2b(b) << 16);
}

// ---------------- embedding: x = emb[id]*sqrt(D) + pos ----------------
__global__ __launch_bounds__(256) void embed_kernel(const int* __restrict__ ids,
    const float* __restrict__ emb, const float* __restrict__ pos, float* __restrict__ x) {
  int row = blockIdx.x;              // 0..2047 = b*S + s
  int s = row & (S_ - 1);
  int id = ids[row];
  const float4* e = (const float4*)(emb + (size_t)id * D_);
  const float4* p = (const float4*)(pos + (size_t)s * D_);
  float4* xo = (float4*)(x + (size_t)row * D_);
  int t = threadIdx.x;               // 256 threads * 4 floats = 1024
  float4 ev = e[t], pv = p[t], r;
  r.x = ev.x * 32.0f + pv.x; r.y = ev.y * 32.0f + pv.y;
  r.z = ev.z * 32.0f + pv.z; r.w = ev.w * 32.0f + pv.w;
  xo[t] = r;
}

// ---------------- layernorm (f32 in) -> bf16 out (block-per-row, round-14) ----
__global__ __launch_bounds__(256) void ln_kernel(const float* __restrict__ x,
    const float* __restrict__ w, const float* __restrict__ b, bf16* __restrict__ h) {
  int row = blockIdx.x, t = threadIdx.x;
  const float4* xr = (const float4*)(x + (size_t)row * D_);
  float4 v = xr[t];
  float s = v.x + v.y + v.z + v.w;
  float s2 = v.x * v.x + v.y * v.y + v.z * v.z + v.w * v.w;
  #pragma unroll
  for (int o = 32; o; o >>= 1) { s += __shfl_down(s, o); s2 += __shfl_down(s2, o); }
  __shared__ float red[8];
  int wave = t >> 6, lane = t & 63;
  if (lane == 0) { red[wave] = s; red[4 + wave] = s2; }
  __syncthreads();
  float mean = (red[0] + red[1] + red[2] + red[3]) * (1.0f / D_);
  float m2   = (red[4] + red[5] + red[6] + red[7]) * (1.0f / D_);
  float rstd = rsqrtf(m2 - mean * mean + 1e-5f);
  float4 wv = ((const float4*)w)[t], bv = ((const float4*)b)[t];
  ushort4 o4;
  o4.x = f2b((v.x - mean) * rstd * wv.x + bv.x);
  o4.y = f2b((v.y - mean) * rstd * wv.y + bv.y);
  o4.z = f2b((v.z - mean) * rstd * wv.z + bv.z);
  o4.w = f2b((v.w - mean) * rstd * wv.w + bv.w);
  ((ushort4*)(h + (size_t)row * D_))[t] = o4;
}

// ------------- weight conversion: stream f32 -> bf16, per-layer strided dst ---
template<int LSHIFT>
__global__ __launch_bounds__(256) void cvt_copy_kernel(const float4* __restrict__ src,
    ushort4* __restrict__ dst, int n4, int wl4) {
  int stride = gridDim.x * 256;
  for (int i = blockIdx.x * 256 + threadIdx.x; i < n4; i += stride) {
    int layer = i >> LSHIFT;
    int r = i & ((1 << LSHIFT) - 1);
    float4 v = src[i];
    ushort4 p;
    p.x = f2b(v.x); p.y = f2b(v.y); p.z = f2b(v.z); p.w = f2b(v.w);
    dst[(size_t)layer * wl4 + r] = p;
  }
}

// ---------------- GEMM: C[M,N] = A[M,K] @ B[N,K]^T (+bias, epilogue by MODE) ---
// round-2 measured-best structure (setprio, 2-buffer 2-phase, XOR swizzle).
template<int MODE>
__global__ __launch_bounds__(256) void gemm_bt(const bf16* __restrict__ A,
    const bf16* __restrict__ Bw,
    const float* __restrict__ b0_, const float* __restrict__ b1_, const float* __restrict__ b2_,
    void* __restrict__ o0, void* __restrict__ o1, void* __restrict__ o2,
    int M, int N, int K, int kspl) {
  __shared__ alignas(16) bf16 As[2][128 * 64];
  __shared__ alignas(16) bf16 Bs[2][128 * 64];
  int tid = threadIdx.x, wave = tid >> 6, lane = tid & 63;
  int nbn = N >> 7;
  int nwg = gridDim.x;
  int bid = blockIdx.x;
  int swz = (bid & 7) * (nwg >> 3) + (bid >> 3);
  int bm = swz / nbn, bn = swz % nbn;
  int m0 = bm << 7, n0 = bn << 7;
  int kbase = blockIdx.z * kspl;
  int wr = wave >> 1, wc = wave & 1;
  int lr = lane & 15, lg = lane >> 4;

  auto stage = [&](int buf, int k0) {
    #pragma unroll
    for (int j = 0; j < 4; j++) {
      int cidx = j * 256 + tid;          // chunk 0..1023
      int r = cidx >> 3, s = cidx & 7;
      int g = s ^ (r & 7);
      bf16* abase = &As[buf][(j * 256 + wave * 64) * 8];
      bf16* bbase = &Bs[buf][(j * 256 + wave * 64) * 8];
      gload_lds16(A  + (size_t)(m0 + r) * K + k0 + g * 8, abase);
      gload_lds16(Bw + (size_t)(n0 + r) * K + k0 + g * 8, bbase);
    }
  };

  f32x4 acc[4][4] = {};
  int nk = kspl >> 6;
  stage(0, kbase);
  __syncthreads();
  int cur = 0;
  for (int t = 0; t < nk; ++t) {
    if (t + 1 < nk) stage(cur ^ 1, kbase + (t + 1) * 64);
    __builtin_amdgcn_s_setprio(1);
    #pragma unroll
    for (int kk = 0; kk < 2; ++kk) {
      bf16x8 af[4], bfr[4];
      #pragma unroll
      for (int f = 0; f < 4; f++) {
        int ra = wr * 64 + f * 16 + lr;
        int rb = wc * 64 + f * 16 + lr;
        af[f]  = *(const bf16x8*)&As[cur][ra * 64 + (((kk * 4 + lg) ^ (ra & 7)) * 8)];
        bfr[f] = *(const bf16x8*)&Bs[cur][rb * 64 + (((kk * 4 + lg) ^ (rb & 7)) * 8)];
      }
      #pragma unroll
      for (int mf = 0; mf < 4; mf++)
        #pragma unroll
        for (int nf = 0; nf < 4; nf++)
          acc[mf][nf] = __builtin_amdgcn_mfma_f32_16x16x32_bf16(af[mf], bfr[nf], acc[mf][nf], 0, 0, 0);
    }
    __builtin_amdgcn_s_setprio(0);
    __syncthreads();
    cur ^= 1;
  }

  #pragma unroll
  for (int mf = 0; mf < 4; mf++) {
    #pragma unroll
    for (int nf = 0; nf < 4; nf++) {
      int n = n0 + wc * 64 + nf * 16 + lr;
      if (MODE == 0 && n >= 2048) {
        int nl = n & 1023;
        int mbase = m0 + wr * 64 + mf * 16 + lg * 4;
        int bb = mbase >> 10, sb = mbase & 1023;
        float bias = b2_[nl];
        ushort4 pk;
        pk.x = f2b(acc[mf][nf][0] + bias);
        pk.y = f2b(acc[mf][nf][1] + bias);
        pk.z = f2b(acc[mf][nf][2] + bias);
        pk.w = f2b(acc[mf][nf][3] + bias);
        *(ushort4*)&((bf16*)o2)[((size_t)(bb * 1024 + nl)) * 1024 + sb] = pk;
      } else {
        #pragma unroll
        for (int i = 0; i < 4; i++) {
          int m = m0 + wr * 64 + mf * 16 + lg * 4 + i;
          float v = acc[mf][nf][i];
          if (MODE == 0) {
            int seg = n >> 10, nl = n & 1023;
            if (seg == 0)      ((bf16*)o0)[(size_t)m * 1024 + nl] = __float2bfloat16(v + b0_[nl]);
            else               ((bf16*)o1)[(size_t)m * 1024 + nl] = __float2bfloat16(v + b1_[nl]);
          } else if (MODE == 1) {
            float bias = (blockIdx.z == 0) ? b0_[n] : 0.0f;
            atomicAdd(&((float*)o0)[(size_t)m * N + n], v + bias);
          } else {
            float g = v + b0_[n];
            float e = __expf(-1.5957691216057308f * (g + 0.044715f * g * g * g));
            ((bf16*)o0)[(size_t)m * N + n] = __float2bfloat16(g / (1.0f + e));
          }
        }
      }
    }
  }
}

// ---------------- flash attention: block = 64 q-rows (4 waves x 16) -----------
// KVBLK=128, swapped QK^T, in-register online softmax in EXP2 DOMAIN
// (t = s * 0.125*log2e; p = 2^(t - mu) == e^(s - m); THR 8 -> 11.54).
// K tile [128k][64d] (8-slot XOR) / V^T tile [64d][128k] (16-slot XOR),
// double-buffered 2-phase. Grid (32 bh, 16 qblk): KV-sharing blocks land on
// the same XCD (linear id == bh mod 8).
__global__ __launch_bounds__(256) void attn_kernel(const bf16* __restrict__ qbuf,
    const bf16* __restrict__ kbuf, const bf16* __restrict__ vT, bf16* __restrict__ obuf) {
  int bh = blockIdx.x;                 // 0..31  (XCD-locality)
  int b = bh >> 4, h = bh & 15;
  int qblk = blockIdx.y * 64;
  int tid = threadIdx.x, wave = tid >> 6, lane = tid & 63;
  int lr = lane & 15, lg = lane >> 4;

  __shared__ alignas(16) bf16 Ks[2][128 * 64];  // [key][d], 8x16B XOR slots
  __shared__ alignas(16) bf16 Vs[2][64 * 128];  // [d][key], 16x16B XOR slots

  auto stage = [&](int buf, int c) {
    int kb = c * 128;
    #pragma unroll
    for (int j = 0; j < 4; j++) {      // K: 1024 chunks, 8 per key-row
      int cidx = j * 256 + tid;
      int r = cidx >> 3, s = cidx & 7, g = s ^ (r & 7);
      gload_lds16(kbuf + (size_t)(b * S_ + kb + r) * D_ + h * 64 + g * 8,
                  &Ks[buf][(j * 256 + wave * 64) * 8]);
    }
    #pragma unroll
    for (int j = 0; j < 4; j++) {      // V: 1024 chunks, 16 per d-row
      int cidx = j * 256 + tid;
      int r = cidx >> 4, s = cidx & 15, g = s ^ (r & 15);
      gload_lds16(vT + (size_t)(b * D_ + h * 64 + r) * S_ + kb + g * 8,
                  &Vs[buf][(j * 256 + wave * 64) * 8]);
    }
  };

  const bf16* qp = qbuf + (size_t)(b * S_ + qblk + wave * 16 + lr) * D_ + h * 64;
  bf16x8 qf0 = *(const bf16x8*)(qp + lg * 8);
  bf16x8 qf1 = *(const bf16x8*)(qp + 32 + lg * 8);

  f32x4 oacc[4] = {};                  // O[q=lg*4+i][d=nf*16+lr]
  float m_run = -1e30f, l_run = 0.0f;  // in exp2 (t) domain
  int x7 = lr & 7;
  const float SC = 0.18033688011112042f;   // 0.125 * log2(e)
  const float THR = 11.541560327111707f;   // 8 * log2(e)

  stage(0, 0);
  __syncthreads();
  int cur = 0;
  for (int c = 0; c < 8; ++c) {
    if (c + 1 < 8) stage(cur ^ 1, c + 1);

    float p[32];
    __builtin_amdgcn_s_setprio(1);
    #pragma unroll
    for (int kg = 0; kg < 8; kg++) {
      int row = kg * 16 + lr;
      bf16x8 k0 = *(const bf16x8*)&Ks[cur][row * 64 + ((lg ^ x7) * 8)];
      bf16x8 k1 = *(const bf16x8*)&Ks[cur][row * 64 + (((4 + lg) ^ x7) * 8)];
      f32x4 s = {};
      s = __builtin_amdgcn_mfma_f32_16x16x32_bf16(k0, qf0, s, 0, 0, 0);
      s = __builtin_amdgcn_mfma_f32_16x16x32_bf16(k1, qf1, s, 0, 0, 0);
      #pragma unroll
      for (int i = 0; i < 4; i++) p[kg * 4 + i] = s[i] * SC;
    }
    __builtin_amdgcn_s_setprio(0);

    float cmax = p[0];
    #pragma unroll
    for (int j = 1; j < 32; j++) cmax = fmaxf(cmax, p[j]);
    cmax = fmaxf(cmax, __shfl_xor(cmax, 16));
    cmax = fmaxf(cmax, __shfl_xor(cmax, 32));

    if (__any(cmax > m_run + THR)) {
      float m_new = fmaxf(m_run, cmax);
      float fsc = exp2f(m_run - m_new);
      m_run = m_new;
      float f0 = __shfl(fsc, lg * 4 + 0);
      float f1 = __shfl(fsc, lg * 4 + 1);
      float f2 = __shfl(fsc, lg * 4 + 2);
      float f3 = __shfl(fsc, lg * 4 + 3);
      #pragma unroll
      for (int nf = 0; nf < 4; nf++) {
        oacc[nf][0] *= f0; oacc[nf][1] *= f1; oacc[nf][2] *= f2; oacc[nf][3] *= f3;
      }
      l_run *= fsc;
    }

    float csum = 0.0f;
    #pragma unroll
    for (int j = 0; j < 32; j++) { p[j] = exp2f(p[j] - m_run); csum += p[j]; }
    csum += __shfl_xor(csum, 16);
    csum += __shfl_xor(csum, 32);
    l_run += csum;

    bf16x8 pf[4];
    int slo = 32 * (lg & 1) + lr, shi = slo + 16;
    bool loh = (lg < 2);
    #pragma unroll
    for (int ks = 0; ks < 4; ks++) {
      unsigned A0 = pk2(p[ks * 8 + 0], p[ks * 8 + 1]);
      unsigned A1 = pk2(p[ks * 8 + 2], p[ks * 8 + 3]);
      unsigned B0 = pk2(p[ks * 8 + 4], p[ks * 8 + 5]);
      unsigned B1 = pk2(p[ks * 8 + 6], p[ks * 8 + 7]);
      unsigned tA0 = __shfl(A0, slo), tB0 = __shfl(B0, slo);
      unsigned tA1 = __shfl(A1, slo), tB1 = __shfl(B1, slo);
      unsigned uA0 = __shfl(A0, shi), uB0 = __shfl(B0, shi);
      unsigned uA1 = __shfl(A1, shi), uB1 = __shfl(B1, shi);
      union { unsigned w[4]; bf16x8 v; } pfu;
      pfu.w[0] = loh ? tA0 : tB0;
      pfu.w[1] = loh ? tA1 : tB1;
      pfu.w[2] = loh ? uA0 : uB0;
      pfu.w[3] = loh ? uA1 : uB1;
      pf[ks] = pfu.v;
    }

    __builtin_amdgcn_s_setprio(1);
    #pragma unroll
    for (int nf = 0; nf < 4; nf++) {
      int rv = nf * 16 + lr;
      int xv = rv & 15;
      #pragma unroll
      for (int ks = 0; ks < 4; ks++) {
        bf16x8 vf = *(const bf16x8*)&Vs[cur][rv * 128 + (((ks * 4 + lg) ^ xv) * 8)];
        oacc[nf] = __builtin_amdgcn_mfma_f32_16x16x32_bf16(pf[ks], vf, oacc[nf], 0, 0, 0);
      }
    }
    __builtin_amdgcn_s_setprio(0);

    __syncthreads();
    cur ^= 1;
  }

  float l0 = __shfl(l_run, lg * 4 + 0);
  float l1 = __shfl(l_run, lg * 4 + 1);
  float l2 = __shfl(l_run, lg * 4 + 2);
  float l3 = __shfl(l_run, lg * 4 + 3);
  float li[4] = {l0, l1, l2, l3};
  #pragma unroll
  for (int i = 0; i < 4; i++) {
    size_t row = (size_t)(b * S_ + qblk + wave * 16 + lg * 4 + i) * D_ + h * 64;
    #pragma unroll
    for (int nf = 0; nf < 4; nf++)
      obuf[row + nf * 16 + lr] = __float2bfloat16(oacc[nf][i] / li[i]);
  }
}

// ---------------- host launch ----------------
extern "C" void kernel_launch(void* const* d_in, const int* in_sizes, int n_in,
                              void* d_out, int out_size, void* d_ws, size_t ws_size,
                              hipStream_t stream) {
  const int*   ids  = (const int*)d_in[0];
  // d_in[1] = attention_mask (all true) -- unused
  const float* emb  = (const float*)d_in[2];
  const float* pos  = (const float*)d_in[3];
  const float* ln1w = (const float*)d_in[4];
  const float* ln1b = (const float*)d_in[5];
  const float* qw = (const float*)d_in[6];  const float* qb = (const float*)d_in[7];
  const float* kw = (const float*)d_in[8];  const float* kb = (const float*)d_in[9];
  const float* vw = (const float*)d_in[10]; const float* vb = (const float*)d_in[11];
  const float* ow = (const float*)d_in[12]; const float* ob = (const float*)d_in[13];
  const float* ln2w = (const float*)d_in[14]; const float* ln2b = (const float*)d_in[15];
  const float* w1 = (const float*)d_in[16]; const float* b1 = (const float*)d_in[17];
  const float* w2 = (const float*)d_in[18]; const float* b2 = (const float*)d_in[19];
  (void)in_sizes; (void)n_in; (void)out_size; (void)ws_size;

  float* x = (float*)d_out;            // residual stream lives in d_out (f32 [2048][1024])
  char* ws = (char*)d_ws;
  const size_t SZ_ACT = (size_t)MTOT * D_ * 2;       // 4 MB bf16
  bf16* h    = (bf16*)(ws);
  bf16* q    = (bf16*)(ws + SZ_ACT);
  bf16* k    = (bf16*)(ws + 2 * SZ_ACT);
  bf16* vt   = (bf16*)(ws + 3 * SZ_ACT);
  bf16* o    = (bf16*)(ws + 4 * SZ_ACT);
  bf16* mid  = (bf16*)(ws + 5 * SZ_ACT);             // 16 MB
  bf16* wbuf = (bf16*)(ws + 5 * SZ_ACT + (size_t)MTOT * F_ * 2);  // 151 MB (layer-major)

  const size_t DD = (size_t)D_ * D_;       // 1048576 (2^20)
  const size_t FD = (size_t)F_ * D_;       // 4194304 (2^22)
  const size_t WL = 4 * DD + 2 * FD;       // 12582912 elements per layer

  const int WL4 = (int)(WL / 4);
  cvt_copy_kernel<18><<<2048, 256, 0, stream>>>((const float4*)qw,
      (ushort4*)(wbuf + 0 * DD), (int)(6 * DD / 4), WL4);
  cvt_copy_kernel<18><<<2048, 256, 0, stream>>>((const float4*)kw,
      (ushort4*)(wbuf + 1 * DD), (int)(6 * DD / 4), WL4);
  cvt_copy_kernel<18><<<2048, 256, 0, stream>>>((const float4*)vw,
      (ushort4*)(wbuf + 2 * DD), (int)(6 * DD / 4), WL4);
  cvt_copy_kernel<18><<<2048, 256, 0, stream>>>((const float4*)ow,
      (ushort4*)(wbuf + 3 * DD), (int)(6 * DD / 4), WL4);
  cvt_copy_kernel<20><<<2048, 256, 0, stream>>>((const float4*)w1,
      (ushort4*)(wbuf + 4 * DD), (int)(6 * FD / 4), WL4);
  cvt_copy_kernel<20><<<2048, 256, 0, stream>>>((const float4*)w2,
      (ushort4*)(wbuf + 4 * DD + FD), (int)(6 * FD / 4), WL4);

  embed_kernel<<<MTOT, 256, 0, stream>>>(ids, emb, pos, x);

  for (int l = 0; l < 6; l++) {
    bf16* wl = wbuf + (size_t)l * WL;

    ln_kernel<<<MTOT, 256, 0, stream>>>(x, ln1w + l * D_, ln1b + l * D_, h);

    // fused QKV: N = 3072, 384 blocks ([qw|kw|vw] contiguous in wl)
    gemm_bt<0><<<dim3(384, 1, 1), 256, 0, stream>>>(h, wl,
        qb + l * D_, kb + l * D_, vb + l * D_, q, k, vt, MTOT, 3072, 1024, 1024);

    // flash attention: 32 (b,h) x 16 q-blocks (XCD-locality axis order)
    attn_kernel<<<dim3(32, 16), 256, 0, stream>>>(q, k, vt, o);

    // x += o @ ow^T + ob   (split-K=2 -> 256 blocks)
    gemm_bt<1><<<dim3(128, 1, 2), 256, 0, stream>>>(o, wl + 3 * DD,
        ob + l * D_, nullptr, nullptr, x, nullptr, nullptr, MTOT, 1024, 1024, 512);

    ln_kernel<<<MTOT, 256, 0, stream>>>(x, ln2w + l * D_, ln2b + l * D_, h);

    // mid = gelu(h @ w1^T + b1), 512 blocks
    gemm_bt<2><<<dim3(512, 1, 1), 256, 0, stream>>>(h, wl + 4 * DD,
        b1 + l * F_, nullptr, nullptr, mid, nullptr, nullptr, MTOT, 4096, 1024, 1024);

    // x += mid @ w2^T + b2   (split-K=2 -> 256 blocks)
    gemm_bt<1><<<dim3(128, 1, 2), 256, 0, stream>>>(mid, wl + 4 * DD + FD,
        b2 + l * D_, nullptr, nullptr, x, nullptr, nullptr, MTOT, 1024, 4096, 2048);
  }
}

// Round 17
// 999.461 us; speedup vs baseline: 1.0405x; 1.0367x over previous
//
#include <hip/hip_runtime.h>
#include <hip/hip_bf16.h>
#include <math.h>

#define D_ 1024
#define H_ 16
#define F_ 4096
#define S_ 1024
#define B_ 2
#define MTOT 2048   // B_*S_

using bf16 = __hip_bfloat16;
typedef __bf16 bf16x8 __attribute__((ext_vector_type(8)));
typedef float f32x4 __attribute__((ext_vector_type(4)));

__device__ __forceinline__ void gload_lds16(const void* g, void* l) {
  __builtin_amdgcn_global_load_lds((const __attribute__((address_space(1))) void*)g,
                                   (__attribute__((address_space(3))) void*)l, 16, 0, 0);
}

__device__ __forceinline__ unsigned short f2b(float f) {
  union { bf16 h; unsigned short u; } c;
  c.h = __float2bfloat16(f);
  return c.u;
}

__device__ __forceinline__ unsigned pk2(float a, float b) {
  return (unsigned)f2b(a) | ((unsigned)f2b(b) << 16);
}

// ---------------- embedding: x = emb[id]*sqrt(D) + pos ----------------
__global__ __launch_bounds__(256) void embed_kernel(const int* __restrict__ ids,
    const float* __restrict__ emb, const float* __restrict__ pos, float* __restrict__ x) {
  int row = blockIdx.x;              // 0..2047 = b*S + s
  int s = row & (S_ - 1);
  int id = ids[row];
  const float4* e = (const float4*)(emb + (size_t)id * D_);
  const float4* p = (const float4*)(pos + (size_t)s * D_);
  float4* xo = (float4*)(x + (size_t)row * D_);
  int t = threadIdx.x;               // 256 threads * 4 floats = 1024
  float4 ev = e[t], pv = p[t], r;
  r.x = ev.x * 32.0f + pv.x; r.y = ev.y * 32.0f + pv.y;
  r.z = ev.z * 32.0f + pv.z; r.w = ev.w * 32.0f + pv.w;
  xo[t] = r;
}

// ---------------- layernorm (f32 in) -> bf16 out (block-per-row) ----------
__global__ __launch_bounds__(256) void ln_kernel(const float* __restrict__ x,
    const float* __restrict__ w, const float* __restrict__ b, bf16* __restrict__ h) {
  int row = blockIdx.x, t = threadIdx.x;
  const float4* xr = (const float4*)(x + (size_t)row * D_);
  float4 v = xr[t];
  float s = v.x + v.y + v.z + v.w;
  float s2 = v.x * v.x + v.y * v.y + v.z * v.z + v.w * v.w;
  #pragma unroll
  for (int o = 32; o; o >>= 1) { s += __shfl_down(s, o); s2 += __shfl_down(s2, o); }
  __shared__ float red[8];
  int wave = t >> 6, lane = t & 63;
  if (lane == 0) { red[wave] = s; red[4 + wave] = s2; }
  __syncthreads();
  float mean = (red[0] + red[1] + red[2] + red[3]) * (1.0f / D_);
  float m2   = (red[4] + red[5] + red[6] + red[7]) * (1.0f / D_);
  float rstd = rsqrtf(m2 - mean * mean + 1e-5f);
  float4 wv = ((const float4*)w)[t], bv = ((const float4*)b)[t];
  ushort4 o4;
  o4.x = f2b((v.x - mean) * rstd * wv.x + bv.x);
  o4.y = f2b((v.y - mean) * rstd * wv.y + bv.y);
  o4.z = f2b((v.z - mean) * rstd * wv.z + bv.z);
  o4.w = f2b((v.w - mean) * rstd * wv.w + bv.w);
  ((ushort4*)(h + (size_t)row * D_))[t] = o4;
}

// ------------- weight conversion: stream f32 -> bf16, per-layer strided dst ---
template<int LSHIFT>
__global__ __launch_bounds__(256) void cvt_copy_kernel(const float4* __restrict__ src,
    ushort4* __restrict__ dst, int n4, int wl4) {
  int stride = gridDim.x * 256;
  for (int i = blockIdx.x * 256 + threadIdx.x; i < n4; i += stride) {
    int layer = i >> LSHIFT;
    int r = i & ((1 << LSHIFT) - 1);
    float4 v = src[i];
    ushort4 p;
    p.x = f2b(v.x); p.y = f2b(v.y); p.z = f2b(v.z); p.w = f2b(v.w);
    dst[(size_t)layer * wl4 + r] = p;
  }
}

// ---------------- GEMM: C[M,N] = A[M,K] @ B[N,K]^T (+bias, epilogue by MODE) ---
// round-2 measured-best structure (setprio, 2-buffer 2-phase, XOR swizzle).
template<int MODE>
__global__ __launch_bounds__(256) void gemm_bt(const bf16* __restrict__ A,
    const bf16* __restrict__ Bw,
    const float* __restrict__ b0_, const float* __restrict__ b1_, const float* __restrict__ b2_,
    void* __restrict__ o0, void* __restrict__ o1, void* __restrict__ o2,
    int M, int N, int K, int kspl) {
  __shared__ alignas(16) bf16 As[2][128 * 64];
  __shared__ alignas(16) bf16 Bs[2][128 * 64];
  int tid = threadIdx.x, wave = tid >> 6, lane = tid & 63;
  int nbn = N >> 7;
  int nwg = gridDim.x;
  int bid = blockIdx.x;
  int swz = (bid & 7) * (nwg >> 3) + (bid >> 3);
  int bm = swz / nbn, bn = swz % nbn;
  int m0 = bm << 7, n0 = bn << 7;
  int kbase = blockIdx.z * kspl;
  int wr = wave >> 1, wc = wave & 1;
  int lr = lane & 15, lg = lane >> 4;

  auto stage = [&](int buf, int k0) {
    #pragma unroll
    for (int j = 0; j < 4; j++) {
      int cidx = j * 256 + tid;          // chunk 0..1023
      int r = cidx >> 3, s = cidx & 7;
      int g = s ^ (r & 7);
      bf16* abase = &As[buf][(j * 256 + wave * 64) * 8];
      bf16* bbase = &Bs[buf][(j * 256 + wave * 64) * 8];
      gload_lds16(A  + (size_t)(m0 + r) * K + k0 + g * 8, abase);
      gload_lds16(Bw + (size_t)(n0 + r) * K + k0 + g * 8, bbase);
    }
  };

  f32x4 acc[4][4] = {};
  int nk = kspl >> 6;
  stage(0, kbase);
  __syncthreads();
  int cur = 0;
  for (int t = 0; t < nk; ++t) {
    if (t + 1 < nk) stage(cur ^ 1, kbase + (t + 1) * 64);
    __builtin_amdgcn_s_setprio(1);
    #pragma unroll
    for (int kk = 0; kk < 2; ++kk) {
      bf16x8 af[4], bfr[4];
      #pragma unroll
      for (int f = 0; f < 4; f++) {
        int ra = wr * 64 + f * 16 + lr;
        int rb = wc * 64 + f * 16 + lr;
        af[f]  = *(const bf16x8*)&As[cur][ra * 64 + (((kk * 4 + lg) ^ (ra & 7)) * 8)];
        bfr[f] = *(const bf16x8*)&Bs[cur][rb * 64 + (((kk * 4 + lg) ^ (rb & 7)) * 8)];
      }
      #pragma unroll
      for (int mf = 0; mf < 4; mf++)
        #pragma unroll
        for (int nf = 0; nf < 4; nf++)
          acc[mf][nf] = __builtin_amdgcn_mfma_f32_16x16x32_bf16(af[mf], bfr[nf], acc[mf][nf], 0, 0, 0);
    }
    __builtin_amdgcn_s_setprio(0);
    __syncthreads();
    cur ^= 1;
  }

  #pragma unroll
  for (int mf = 0; mf < 4; mf++) {
    #pragma unroll
    for (int nf = 0; nf < 4; nf++) {
      int n = n0 + wc * 64 + nf * 16 + lr;
      if (MODE == 0 && n >= 2048) {
        int nl = n & 1023;
        int mbase = m0 + wr * 64 + mf * 16 + lg * 4;
        int bb = mbase >> 10, sb = mbase & 1023;
        float bias = b2_[nl];
        ushort4 pk;
        pk.x = f2b(acc[mf][nf][0] + bias);
        pk.y = f2b(acc[mf][nf][1] + bias);
        pk.z = f2b(acc[mf][nf][2] + bias);
        pk.w = f2b(acc[mf][nf][3] + bias);
        *(ushort4*)&((bf16*)o2)[((size_t)(bb * 1024 + nl)) * 1024 + sb] = pk;
      } else {
        #pragma unroll
        for (int i = 0; i < 4; i++) {
          int m = m0 + wr * 64 + mf * 16 + lg * 4 + i;
          float v = acc[mf][nf][i];
          if (MODE == 0) {
            int seg = n >> 10, nl = n & 1023;
            if (seg == 0)      ((bf16*)o0)[(size_t)m * 1024 + nl] = __float2bfloat16(v + b0_[nl]);
            else               ((bf16*)o1)[(size_t)m * 1024 + nl] = __float2bfloat16(v + b1_[nl]);
          } else if (MODE == 1) {
            float bias = (blockIdx.z == 0) ? b0_[n] : 0.0f;
            atomicAdd(&((float*)o0)[(size_t)m * N + n], v + bias);
          } else {
            float g = v + b0_[n];
            float e = __expf(-1.5957691216057308f * (g + 0.044715f * g * g * g));
            ((bf16*)o0)[(size_t)m * N + n] = __float2bfloat16(g / (1.0f + e));
          }
        }
      }
    }
  }
}

// ---------------- flash attention: block = 64 q-rows (4 waves x 16) -----------
// KVBLK=128, swapped QK^T, in-register online softmax in EXP2 DOMAIN via
// __builtin_amdgcn_exp2f (bare v_exp_f32, no libcall guard code).
// t = s * 0.125*log2e; p = 2^(t - mu) == e^(s - m); THR 8 -> 11.54.
// K tile [128k][64d] (8-slot XOR) / V^T tile [64d][128k] (16-slot XOR),
// double-buffered 2-phase. Grid (32 bh, 16 qblk): KV-sharing blocks on same XCD.
__global__ __launch_bounds__(256) void attn_kernel(const bf16* __restrict__ qbuf,
    const bf16* __restrict__ kbuf, const bf16* __restrict__ vT, bf16* __restrict__ obuf) {
  int bh = blockIdx.x;                 // 0..31  (XCD-locality)
  int b = bh >> 4, h = bh & 15;
  int qblk = blockIdx.y * 64;
  int tid = threadIdx.x, wave = tid >> 6, lane = tid & 63;
  int lr = lane & 15, lg = lane >> 4;

  __shared__ alignas(16) bf16 Ks[2][128 * 64];  // [key][d], 8x16B XOR slots
  __shared__ alignas(16) bf16 Vs[2][64 * 128];  // [d][key], 16x16B XOR slots

  auto stage = [&](int buf, int c) {
    int kb = c * 128;
    #pragma unroll
    for (int j = 0; j < 4; j++) {      // K: 1024 chunks, 8 per key-row
      int cidx = j * 256 + tid;
      int r = cidx >> 3, s = cidx & 7, g = s ^ (r & 7);
      gload_lds16(kbuf + (size_t)(b * S_ + kb + r) * D_ + h * 64 + g * 8,
                  &Ks[buf][(j * 256 + wave * 64) * 8]);
    }
    #pragma unroll
    for (int j = 0; j < 4; j++) {      // V: 1024 chunks, 16 per d-row
      int cidx = j * 256 + tid;
      int r = cidx >> 4, s = cidx & 15, g = s ^ (r & 15);
      gload_lds16(vT + (size_t)(b * D_ + h * 64 + r) * S_ + kb + g * 8,
                  &Vs[buf][(j * 256 + wave * 64) * 8]);
    }
  };

  const bf16* qp = qbuf + (size_t)(b * S_ + qblk + wave * 16 + lr) * D_ + h * 64;
  bf16x8 qf0 = *(const bf16x8*)(qp + lg * 8);
  bf16x8 qf1 = *(const bf16x8*)(qp + 32 + lg * 8);

  f32x4 oacc[4] = {};                  // O[q=lg*4+i][d=nf*16+lr]
  float m_run = -1e30f, l_run = 0.0f;  // in exp2 (t) domain
  int x7 = lr & 7;
  const float SC = 0.18033688011112042f;   // 0.125 * log2(e)
  const float THR = 11.541560327111707f;   // 8 * log2(e)

  stage(0, 0);
  __syncthreads();
  int cur = 0;
  for (int c = 0; c < 8; ++c) {
    if (c + 1 < 8) stage(cur ^ 1, c + 1);

    float p[32];
    __builtin_amdgcn_s_setprio(1);
    #pragma unroll
    for (int kg = 0; kg < 8; kg++) {
      int row = kg * 16 + lr;
      bf16x8 k0 = *(const bf16x8*)&Ks[cur][row * 64 + ((lg ^ x7) * 8)];
      bf16x8 k1 = *(const bf16x8*)&Ks[cur][row * 64 + (((4 + lg) ^ x7) * 8)];
      f32x4 s = {};
      s = __builtin_amdgcn_mfma_f32_16x16x32_bf16(k0, qf0, s, 0, 0, 0);
      s = __builtin_amdgcn_mfma_f32_16x16x32_bf16(k1, qf1, s, 0, 0, 0);
      #pragma unroll
      for (int i = 0; i < 4; i++) p[kg * 4 + i] = s[i] * SC;
    }
    __builtin_amdgcn_s_setprio(0);

    float cmax = p[0];
    #pragma unroll
    for (int j = 1; j < 32; j++) cmax = fmaxf(cmax, p[j]);
    cmax = fmaxf(cmax, __shfl_xor(cmax, 16));
    cmax = fmaxf(cmax, __shfl_xor(cmax, 32));

    if (__any(cmax > m_run + THR)) {
      float m_new = fmaxf(m_run, cmax);
      float fsc = __builtin_amdgcn_exp2f(m_run - m_new);
      m_run = m_new;
      float f0 = __shfl(fsc, lg * 4 + 0);
      float f1 = __shfl(fsc, lg * 4 + 1);
      float f2 = __shfl(fsc, lg * 4 + 2);
      float f3 = __shfl(fsc, lg * 4 + 3);
      #pragma unroll
      for (int nf = 0; nf < 4; nf++) {
        oacc[nf][0] *= f0; oacc[nf][1] *= f1; oacc[nf][2] *= f2; oacc[nf][3] *= f3;
      }
      l_run *= fsc;
    }

    float csum = 0.0f;
    #pragma unroll
    for (int j = 0; j < 32; j++) { p[j] = __builtin_amdgcn_exp2f(p[j] - m_run); csum += p[j]; }
    csum += __shfl_xor(csum, 16);
    csum += __shfl_xor(csum, 32);
    l_run += csum;

    bf16x8 pf[4];
    int slo = 32 * (lg & 1) + lr, shi = slo + 16;
    bool loh = (lg < 2);
    #pragma unroll
    for (int ks = 0; ks < 4; ks++) {
      unsigned A0 = pk2(p[ks * 8 + 0], p[ks * 8 + 1]);
      unsigned A1 = pk2(p[ks * 8 + 2], p[ks * 8 + 3]);
      unsigned B0 = pk2(p[ks * 8 + 4], p[ks * 8 + 5]);
      unsigned B1 = pk2(p[ks * 8 + 6], p[ks * 8 + 7]);
      unsigned tA0 = __shfl(A0, slo), tB0 = __shfl(B0, slo);
      unsigned tA1 = __shfl(A1, slo), tB1 = __shfl(B1, slo);
      unsigned uA0 = __shfl(A0, shi), uB0 = __shfl(B0, shi);
      unsigned uA1 = __shfl(A1, shi), uB1 = __shfl(B1, shi);
      union { unsigned w[4]; bf16x8 v; } pfu;
      pfu.w[0] = loh ? tA0 : tB0;
      pfu.w[1] = loh ? tA1 : tB1;
      pfu.w[2] = loh ? uA0 : uB0;
      pfu.w[3] = loh ? uA1 : uB1;
      pf[ks] = pfu.v;
    }

    __builtin_amdgcn_s_setprio(1);
    #pragma unroll
    for (int nf = 0; nf < 4; nf++) {
      int rv = nf * 16 + lr;
      int xv = rv & 15;
      #pragma unroll
      for (int ks = 0; ks < 4; ks++) {
        bf16x8 vf = *(const bf16x8*)&Vs[cur][rv * 128 + (((ks * 4 + lg) ^ xv) * 8)];
        oacc[nf] = __builtin_amdgcn_mfma_f32_16x16x32_bf16(pf[ks], vf, oacc[nf], 0, 0, 0);
      }
    }
    __builtin_amdgcn_s_setprio(0);

    __syncthreads();
    cur ^= 1;
  }

  float l0 = __shfl(l_run, lg * 4 + 0);
  float l1 = __shfl(l_run, lg * 4 + 1);
  float l2 = __shfl(l_run, lg * 4 + 2);
  float l3 = __shfl(l_run, lg * 4 + 3);
  float li[4] = {l0, l1, l2, l3};
  #pragma unroll
  for (int i = 0; i < 4; i++) {
    size_t row = (size_t)(b * S_ + qblk + wave * 16 + lg * 4 + i) * D_ + h * 64;
    #pragma unroll
    for (int nf = 0; nf < 4; nf++)
      obuf[row + nf * 16 + lr] = __float2bfloat16(oacc[nf][i] / li[i]);
  }
}

// ---------------- host launch ----------------
extern "C" void kernel_launch(void* const* d_in, const int* in_sizes, int n_in,
                              void* d_out, int out_size, void* d_ws, size_t ws_size,
                              hipStream_t stream) {
  const int*   ids  = (const int*)d_in[0];
  // d_in[1] = attention_mask (all true) -- unused
  const float* emb  = (const float*)d_in[2];
  const float* pos  = (const float*)d_in[3];
  const float* ln1w = (const float*)d_in[4];
  const float* ln1b = (const float*)d_in[5];
  const float* qw = (const float*)d_in[6];  const float* qb = (const float*)d_in[7];
  const float* kw = (const float*)d_in[8];  const float* kb = (const float*)d_in[9];
  const float* vw = (const float*)d_in[10]; const float* vb = (const float*)d_in[11];
  const float* ow = (const float*)d_in[12]; const float* ob = (const float*)d_in[13];
  const float* ln2w = (const float*)d_in[14]; const float* ln2b = (const float*)d_in[15];
  const float* w1 = (const float*)d_in[16]; const float* b1 = (const float*)d_in[17];
  const float* w2 = (const float*)d_in[18]; const float* b2 = (const float*)d_in[19];
  (void)in_sizes; (void)n_in; (void)out_size; (void)ws_size;

  float* x = (float*)d_out;            // residual stream lives in d_out (f32 [2048][1024])
  char* ws = (char*)d_ws;
  const size_t SZ_ACT = (size_t)MTOT * D_ * 2;       // 4 MB bf16
  bf16* h    = (bf16*)(ws);
  bf16* q    = (bf16*)(ws + SZ_ACT);
  bf16* k    = (bf16*)(ws + 2 * SZ_ACT);
  bf16* vt   = (bf16*)(ws + 3 * SZ_ACT);
  bf16* o    = (bf16*)(ws + 4 * SZ_ACT);
  bf16* mid  = (bf16*)(ws + 5 * SZ_ACT);             // 16 MB
  bf16* wbuf = (bf16*)(ws + 5 * SZ_ACT + (size_t)MTOT * F_ * 2);  // 151 MB (layer-major)

  const size_t DD = (size_t)D_ * D_;       // 1048576 (2^20)
  const size_t FD = (size_t)F_ * D_;       // 4194304 (2^22)
  const size_t WL = 4 * DD + 2 * FD;       // 12582912 elements per layer

  const int WL4 = (int)(WL / 4);
  cvt_copy_kernel<18><<<2048, 256, 0, stream>>>((const float4*)qw,
      (ushort4*)(wbuf + 0 * DD), (int)(6 * DD / 4), WL4);
  cvt_copy_kernel<18><<<2048, 256, 0, stream>>>((const float4*)kw,
      (ushort4*)(wbuf + 1 * DD), (int)(6 * DD / 4), WL4);
  cvt_copy_kernel<18><<<2048, 256, 0, stream>>>((const float4*)vw,
      (ushort4*)(wbuf + 2 * DD), (int)(6 * DD / 4), WL4);
  cvt_copy_kernel<18><<<2048, 256, 0, stream>>>((const float4*)ow,
      (ushort4*)(wbuf + 3 * DD), (int)(6 * DD / 4), WL4);
  cvt_copy_kernel<20><<<2048, 256, 0, stream>>>((const float4*)w1,
      (ushort4*)(wbuf + 4 * DD), (int)(6 * FD / 4), WL4);
  cvt_copy_kernel<20><<<2048, 256, 0, stream>>>((const float4*)w2,
      (ushort4*)(wbuf + 4 * DD + FD), (int)(6 * FD / 4), WL4);

  embed_kernel<<<MTOT, 256, 0, stream>>>(ids, emb, pos, x);

  for (int l = 0; l < 6; l++) {
    bf16* wl = wbuf + (size_t)l * WL;

    ln_kernel<<<MTOT, 256, 0, stream>>>(x, ln1w + l * D_, ln1b + l * D_, h);

    // fused QKV: N = 3072, 384 blocks ([qw|kw|vw] contiguous in wl)
    gemm_bt<0><<<dim3(384, 1, 1), 256, 0, stream>>>(h, wl,
        qb + l * D_, kb + l * D_, vb + l * D_, q, k, vt, MTOT, 3072, 1024, 1024);

    // flash attention: 32 (b,h) x 16 q-blocks (XCD-locality axis order)
    attn_kernel<<<dim3(32, 16), 256, 0, stream>>>(q, k, vt, o);

    // x += o @ ow^T + ob   (split-K=2 -> 256 blocks)
    gemm_bt<1><<<dim3(128, 1, 2), 256, 0, stream>>>(o, wl + 3 * DD,
        ob + l * D_, nullptr, nullptr, x, nullptr, nullptr, MTOT, 1024, 1024, 512);

    ln_kernel<<<MTOT, 256, 0, stream>>>(x, ln2w + l * D_, ln2b + l * D_, h);

    // mid = gelu(h @ w1^T + b1), 512 blocks
    gemm_bt<2><<<dim3(512, 1, 1), 256, 0, stream>>>(h, wl + 4 * DD,
        b1 + l * F_, nullptr, nullptr, mid, nullptr, nullptr, MTOT, 4096, 1024, 1024);

    // x += mid @ w2^T + b2   (split-K=2 -> 256 blocks)
    gemm_bt<1><<<dim3(128, 1, 2), 256, 0, stream>>>(mid, wl + 4 * DD + FD,
        b2 + l * D_, nullptr, nullptr, x, nullptr, nullptr, MTOT, 1024, 4096, 2048);
  }
}